// Round 1
// baseline (1108.914 us; speedup 1.0000x reference)
//
#include <hip/hip_runtime.h>
#include <stdint.h>

// ---------- types ----------
typedef __bf16 bf16x8 __attribute__((ext_vector_type(8)));
typedef float  f32x4  __attribute__((ext_vector_type(4)));

#define AS1 __attribute__((address_space(1)))
#define AS3 __attribute__((address_space(3)))

// async global->LDS, 16B per lane; LDS dest = wave-uniform base + lane*16
__device__ __forceinline__ void gload_lds16(const void* g, void* l) {
    __builtin_amdgcn_global_load_lds((const AS1 uint32_t*)g, (AS3 uint32_t*)l, 16, 0, 0);
}

// Problem constants: B=32, c_in=64, N=512, L=64, K=3, c_out=64
// j index = k*512 + n  (contraction dim, 1536)
// f2 index = o*64 + l  (output "column" dim, 4096)

// ---------- T2 = 2*adj@adj - I  (fp32, 1 MiB in ws) ----------
__global__ __launch_bounds__(256) void k_t2(const float* __restrict__ adj,
                                            float* __restrict__ T2f) {
    const int q = blockIdx.x, tx = threadIdx.x;
    float a0 = 0.f, a1 = 0.f;
    for (int m = 0; m < 512; ++m) {
        const float av = adj[q*512 + m];           // wave-uniform -> scalar load
        a0 += av * adj[m*512 + tx];
        a1 += av * adj[m*512 + tx + 256];
    }
    T2f[q*512 + tx      ] = 2.f*a0 - ((q == tx      ) ? 1.f : 0.f);
    T2f[q*512 + tx + 256] = 2.f*a1 - ((q == tx + 256) ? 1.f : 0.f);
}

// ---------- W2[f=k*64+o][c] = bf16(W[o][c*3+k]) ----------
__global__ __launch_bounds__(256) void k_w2(const float* __restrict__ W,
                                            __bf16* __restrict__ W2bf) {
    const int t = blockIdx.x*256 + threadIdx.x;    // 48*256 = 12288 = 192*64
    const int f = t >> 6, c = t & 63;
    const int k = f >> 6, o = f & 63;
    W2bf[t] = (__bf16)W[o*192 + c*3 + k];
}

// ---------- A-build: Abf[bb][q][j] = bf16(ds[b,q,n] * T_k[q,n]) ----------
__global__ __launch_bounds__(256) void k_abuild(const float* __restrict__ ds,
                                                const float* __restrict__ adj,
                                                const float* __restrict__ T2f,
                                                __bf16* __restrict__ Abf, int b0) {
    const int bx = blockIdx.x;
    const int bb = bx >> 9, q = bx & 511;
    const int b  = b0 + bb;
    const float* dsr  = ds  + ((size_t)b*512 + q)*512;
    __bf16*      arow = Abf + ((size_t)bb*512 + q)*1536;
    for (int j = threadIdx.x; j < 1536; j += 256) {
        const int k = j >> 9, n = j & 511;
        float tv;
        if      (k == 0) tv = (q == n) ? 1.0f : 0.0f;
        else if (k == 1) tv = adj[q*512 + n];
        else             tv = T2f[q*512 + n];
        arow[j] = (__bf16)(dsr[n] * tv);
    }
}

// ---------- Stage 1: zT[bb][(o,l)][(k,n)] = bf16( sum_c W2[f][c]*x[b,c,n,l] ) ----------
// Block = (bb, ng, lg): n-range 32, l-range 4. MFMA [192 x 64] @ [64 x 128].
// LDS: W2s[192][72] (27648B) + Xs[128][72] (18432B); epilogue reuses as Ds[192][136] (52224B).
__global__ __launch_bounds__(256) void k_zprep(const float* __restrict__ x,
                                               const __bf16* __restrict__ W2bf,
                                               __bf16* __restrict__ zT, int b0) {
    __shared__ __align__(16) char lds_raw[52224];
    __bf16* W2s = (__bf16*)lds_raw;              // [192][72] padded (rows 144B, 16B-aligned)
    __bf16* Xs  = (__bf16*)(lds_raw + 27648);    // [128][72] padded, layout [m'][c]
    __bf16* Dsh = (__bf16*)lds_raw;              // [192][136] (reused after barrier)

    const int t = threadIdx.x, lane = t & 63, w = t >> 6;
    const int bx = blockIdx.x;
    const int bb = bx >> 8;  const int r = bx & 255;
    const int ng = r >> 4, lg = r & 15;          // lg fastest => adjacent blocks share x cachelines
    const int l0 = lg*4, n0 = ng*32;
    const int b  = b0 + bb;

    // W2 -> LDS (padded rows)
    #pragma unroll
    for (int i = 0; i < 6; ++i) {
        const int u = t + 256*i, f = u >> 3, seg = u & 7;
        *(bf16x8*)(W2s + f*72 + seg*8) = *(const bf16x8*)(W2bf + f*64 + seg*8);
    }
    // x -> LDS, fp32->bf16, transpose to [m' = lp*32+nn][c]
    #pragma unroll
    for (int p = 0; p < 8; ++p) {
        const int u = t + 256*p, c = u >> 5, nn = u & 31;
        const float4 v = *(const float4*)(x + (((size_t)b*64 + c)*512 + (n0 + nn))*64 + l0);
        Xs[(nn     )*72 + c] = (__bf16)v.x;
        Xs[(nn + 32)*72 + c] = (__bf16)v.y;
        Xs[(nn + 64)*72 + c] = (__bf16)v.z;
        Xs[(nn + 96)*72 + c] = (__bf16)v.w;
    }
    __syncthreads();

    f32x4 acc[3][8] = {};
    const int fw = w*48, m15 = lane & 15, quad = lane >> 4;
    #pragma unroll
    for (int ks = 0; ks < 2; ++ks) {
        const int c0 = ks*32 + quad*8;
        bf16x8 a[3], bv[8];
        #pragma unroll
        for (int i = 0; i < 3; ++i)
            a[i] = *(const bf16x8*)(W2s + (fw + i*16 + m15)*72 + c0);
        #pragma unroll
        for (int j = 0; j < 8; ++j)
            bv[j] = *(const bf16x8*)(Xs + (j*16 + m15)*72 + c0);
        #pragma unroll
        for (int i = 0; i < 3; ++i)
            #pragma unroll
            for (int j = 0; j < 8; ++j)
                acc[i][j] = __builtin_amdgcn_mfma_f32_16x16x32_bf16(a[i], bv[j], acc[i][j], 0, 0, 0);
    }
    __syncthreads();

    // D (C-layout: row=quad*4+rr, col=m') -> Dsh[f][m'] as bf16
    #pragma unroll
    for (int i = 0; i < 3; ++i)
        #pragma unroll
        for (int j = 0; j < 8; ++j) {
            const int f = fw + i*16 + quad*4, m = j*16 + m15;
            #pragma unroll
            for (int rr = 0; rr < 4; ++rr)
                Dsh[(f + rr)*136 + m] = (__bf16)acc[i][j][rr];
        }
    __syncthreads();

    // transpose-store: for (f=(k,o), l') write 32-long n-run (64B contiguous)
    #pragma unroll
    for (int i = 0; i < 3; ++i) {
        const int u = t + 256*i, f = u >> 2, lp = u & 3;
        const int k = f >> 6, o = f & 63;
        __bf16* dst = zT + ((size_t)bb*4096 + o*64 + (l0 + lp))*1536 + k*512 + n0;
        const __bf16* srcp = Dsh + f*136 + lp*32;
        *(bf16x8*)(dst +  0) = *(const bf16x8*)(srcp +  0);
        *(bf16x8*)(dst +  8) = *(const bf16x8*)(srcp +  8);
        *(bf16x8*)(dst + 16) = *(const bf16x8*)(srcp + 16);
        *(bf16x8*)(dst + 24) = *(const bf16x8*)(srcp + 24);
    }
}

// ---------- Stage 2: out[b][o][q][l] = A_b[512x1536] @ zT_b^T + bias ----------
// m97-style: 128x128 tile, BK=32, 4 waves (2x2 of 64x64), global_load_lds width 16.
__global__ __launch_bounds__(256) void k_gemm(const __bf16* __restrict__ Abf,
                                              const __bf16* __restrict__ zT,
                                              const float* __restrict__ bias,
                                              float* __restrict__ out, int b0) {
    __shared__ __align__(16) __bf16 As[128*32];
    __shared__ __align__(16) __bf16 Bs[128*32];
    const int t = threadIdx.x, lane = t & 63, w = t >> 6;
    const int bx = blockIdx.x;
    const int bb = bx >> 7;  const int r = bx & 127;
    const int qt = r & 3, ft = r >> 2;          // qt fastest => 4 blocks share same B rows in L2
    const int q0 = qt*128, f20 = ft*128;
    const __bf16* Ab = Abf + (size_t)bb*512 *1536;
    const __bf16* Bb = zT  + (size_t)bb*4096*1536;
    const int lrow = lane >> 2, lseg = lane & 3;
    const int m15 = lane & 15, quad = lane >> 4;
    const int wq = (w >> 1)*64, wf = (w & 1)*64;

    f32x4 acc[4][4] = {};
    for (int j0 = 0; j0 < 1536; j0 += 32) {
        #pragma unroll
        for (int i = 0; i < 2; ++i) {
            const int rb = (w*2 + i)*16;        // 16 rows per wave-instr, LDS dest = base+lane*16
            gload_lds16(Ab + ((size_t)(q0  + rb + lrow))*1536 + j0 + lseg*8, As + rb*32);
            gload_lds16(Bb + ((size_t)(f20 + rb + lrow))*1536 + j0 + lseg*8, Bs + rb*32);
        }
        __syncthreads();
        bf16x8 av[4], bv[4];
        const int co = quad*8;
        #pragma unroll
        for (int i = 0; i < 4; ++i) av[i] = *(const bf16x8*)(As + (wq + i*16 + m15)*32 + co);
        #pragma unroll
        for (int j = 0; j < 4; ++j) bv[j] = *(const bf16x8*)(Bs + (wf + j*16 + m15)*32 + co);
        #pragma unroll
        for (int i = 0; i < 4; ++i)
            #pragma unroll
            for (int j = 0; j < 4; ++j)
                acc[i][j] = __builtin_amdgcn_mfma_f32_16x16x32_bf16(av[i], bv[j], acc[i][j], 0, 0, 0);
        __syncthreads();
    }

    const int b = b0 + bb;
    #pragma unroll
    for (int j = 0; j < 4; ++j) {
        const int f2 = f20 + wf + j*16 + m15;
        const int o = f2 >> 6, l = f2 & 63;
        const float bi = bias[o];
        #pragma unroll
        for (int i = 0; i < 4; ++i) {
            const int qb = q0 + wq + i*16 + quad*4;
            float* dst = out + (((size_t)b*64 + o)*512 + qb)*64 + l;
            dst[  0] = acc[i][j][0] + bi;       // q-stride in out is 64 floats
            dst[ 64] = acc[i][j][1] + bi;
            dst[128] = acc[i][j][2] + bi;
            dst[192] = acc[i][j][3] + bi;
        }
    }
}

// ---------- host ----------
extern "C" void kernel_launch(void* const* d_in, const int* in_sizes, int n_in,
                              void* d_out, int out_size, void* d_ws, size_t ws_size,
                              hipStream_t stream) {
    (void)in_sizes; (void)n_in; (void)out_size;
    const float* x    = (const float*)d_in[0];
    const float* adj  = (const float*)d_in[1];
    const float* ds   = (const float*)d_in[2];
    const float* W    = (const float*)d_in[3];
    const float* bias = (const float*)d_in[4];
    float* out = (float*)d_out;
    char*  ws  = (char*)d_ws;

    float*  T2f  = (float*)ws;                      // 512*512*4 = 1 MiB
    __bf16* W2bf = (__bf16*)(ws + (1u << 20));      // 24576 B
    char*   chunk0 = ws + (1u << 20) + 32768;

    const size_t abytes = (size_t)512 *1536*2;      // per-b Abf  (1.5 MiB)
    const size_t zbytes = (size_t)4096*1536*2;      // per-b zT   (12 MiB)
    const size_t perb   = abytes + zbytes;
    const size_t head   = (1u << 20) + 32768;

    int bpc = 1;                                    // batches per chunk, sized to ws
    if (ws_size > head) {
        size_t a = (ws_size - head) / perb;
        bpc = (a < 1) ? 1 : (a > 32 ? 32 : (int)a);
    }

    k_t2<<<dim3(512), dim3(256), 0, stream>>>(adj, T2f);
    k_w2<<<dim3(48),  dim3(256), 0, stream>>>(W, W2bf);

    __bf16* Abf = (__bf16*)chunk0;
    __bf16* zTp = (__bf16*)(chunk0 + (size_t)bpc*abytes);
    for (int b0 = 0; b0 < 32; b0 += bpc) {
        const int bc = (32 - b0 < bpc) ? (32 - b0) : bpc;
        k_abuild<<<dim3(bc*512), dim3(256), 0, stream>>>(ds, adj, T2f, Abf, b0);
        k_zprep <<<dim3(bc*256), dim3(256), 0, stream>>>(x, W2bf, zTp, b0);
        k_gemm  <<<dim3(bc*128), dim3(256), 0, stream>>>(Abf, zTp, bias, out, b0);
    }
}